// Round 15
// baseline (2609.049 us; speedup 1.0000x reference)
//
#include <hip/hip_runtime.h>
#include <hip/hip_bf16.h>
#include <math.h>

#define N_USERS 16384
#define N_ITEMS 8192
#define N_TOTAL 24576
#define EMB_D 64
#define IMG_DIM 4096
#define TXT_DIM 384
#define K_TOP 10
#define N_CAND 16
#define NNZ_E 786432
#define NTILE 64                 // N_ITEMS / 128
#define TRI_BLOCKS (NTILE * (NTILE + 1) / 2)   // 2080
#define LDS_ST 129

typedef _Float16 f16x8 __attribute__((ext_vector_type(8)));
typedef float f32x4 __attribute__((ext_vector_type(4)));

#define AS1 __attribute__((address_space(1)))
#define AS3 __attribute__((address_space(3)))

__device__ __forceinline__ float leaky01(float x){ return x >= 0.f ? x : 0.01f * x; }

__device__ __forceinline__ void gld16(const void* g, void* l) {
  __builtin_amdgcn_global_load_lds((const AS1 unsigned int*)g, (AS3 unsigned int*)l, 16, 0, 0);
}

__device__ __forceinline__ bool beats(float v, int i, float u, int j) {
  return v > u || (v == u && i < j);
}

__device__ __forceinline__ float h2f(unsigned short u) {
  _Float16 h = __builtin_bit_cast(_Float16, u);
  return (float)h;
}
__device__ __forceinline__ unsigned short f2h(float v) {
  _Float16 h = (_Float16)v;
  return __builtin_bit_cast(unsigned short, h);
}

// ---------------- fill supertile tile map (once; reused by all graphs) ----------------
__global__ __launch_bounds__(256) void fill_map_k(int* __restrict__ map) {
  int b = blockIdx.x * 256 + threadIdx.x;
  if (b >= TRI_BLOCKS) return;
  int tileX, tileY;
  if (b < 1792) {               // 28 strict-upper supertiles, 64 tiles each
    int s = b >> 6, w = b & 63;
    int sy = 0, rem = 7;
    while (s >= rem) { s -= rem; sy++; rem--; }
    int sx = sy + 1 + s;
    tileY = sy * 8 + (w >> 3);
    tileX = sx * 8 + (w & 7);
  } else {                      // 8 diagonal supertiles, 36 tiles each
    int b2 = b - 1792;
    int sd = b2 / 36, w = b2 - sd * 36;
    int i = 0, rem = 8;
    while (w >= rem) { w -= rem; i++; rem--; }
    tileY = sd * 8 + i;
    tileX = sd * 8 + i + w;
  }
  map[b] = (tileY << 16) | tileX;
}

// ---------------- fp16 MFMA sim GEMM -> fp32 sim (tri grid; r3's exact 64-VGPR epilogue) ----------------
__global__ __launch_bounds__(256) void sim_mfma_tri_k(const unsigned short* __restrict__ Zh,
                                                      float* __restrict__ C, int K,
                                                      const int* __restrict__ tile_map) {
  __shared__ unsigned short smA[128 * 32];
  __shared__ unsigned short smB[128 * 32];
  const int tid = threadIdx.x;
  const int lane = tid & 63;
  const int wid = tid >> 6;
  const int wr = wid >> 1, wc = wid & 1;

  int tm = tile_map[blockIdx.x];   // uniform -> scalar load
  const int tileY = tm >> 16;
  const int tileX = tm & 0xffff;
  const int bRow = tileY * 128;
  const int bCol = tileX * 128;

  f32x4 acc[4][4];
  const f32x4 fzero = {0.f, 0.f, 0.f, 0.f};
  #pragma unroll
  for (int m = 0; m < 4; m++)
    #pragma unroll
    for (int n = 0; n < 4; n++) acc[m][n] = fzero;

  const int u0 = (wid * 2 + 0) * 64 + lane;
  const int u1 = (wid * 2 + 1) * 64 + lane;
  const int ar0 = u0 >> 2, ac0 = (u0 & 3) * 8;
  const int ar1 = u1 >> 2, ac1 = (u1 & 3) * 8;
  const unsigned offA0 = ((unsigned)(bRow + ar0) * (unsigned)K + (unsigned)ac0) * 2u;
  const unsigned offA1 = ((unsigned)(bRow + ar1) * (unsigned)K + (unsigned)ac1) * 2u;
  const unsigned offB0 = ((unsigned)(bCol + ar0) * (unsigned)K + (unsigned)ac0) * 2u;
  const unsigned offB1 = ((unsigned)(bCol + ar1) * (unsigned)K + (unsigned)ac1) * 2u;
  const char* Zb = (const char*)Zh;
  unsigned short* ldsA0 = smA + (wid * 2 + 0) * 512;
  unsigned short* ldsA1 = smA + (wid * 2 + 1) * 512;
  unsigned short* ldsB0 = smB + (wid * 2 + 0) * 512;
  unsigned short* ldsB1 = smB + (wid * 2 + 1) * 512;

  const int kc = lane >> 4;
  const int fr = lane & 15;

  for (unsigned kb = 0; kb < (unsigned)K * 2u; kb += 64u) {
    __syncthreads();
    gld16(Zb + (offA0 + kb), ldsA0);
    gld16(Zb + (offA1 + kb), ldsA1);
    gld16(Zb + (offB0 + kb), ldsB0);
    gld16(Zb + (offB1 + kb), ldsB1);
    __syncthreads();

    f16x8 a[4], b[4];
    #pragma unroll
    for (int m = 0; m < 4; m++)
      a[m] = *(const f16x8*)&smA[(wr * 64 + m * 16 + fr) * 32 + kc * 8];
    #pragma unroll
    for (int n = 0; n < 4; n++)
      b[n] = *(const f16x8*)&smB[(wc * 64 + n * 16 + fr) * 32 + kc * 8];
    #pragma unroll
    for (int m = 0; m < 4; m++)
      #pragma unroll
      for (int n = 0; n < 4; n++)
        acc[m][n] = __builtin_amdgcn_mfma_f32_16x16x32_f16(a[m], b[n], acc[m][n], 0, 0, 0);
  }

  // fp32 direct store (r3-proven 64-VGPR epilogue; no conversion work)
  const int crow = bRow + wr * 64 + (lane >> 4) * 4;
  const int ccol = bCol + wc * 64 + (lane & 15);
  #pragma unroll
  for (int m = 0; m < 4; m++)
    #pragma unroll
    for (int n = 0; n < 4; n++)
      #pragma unroll
      for (int r = 0; r < 4; r++)
        C[(size_t)(crow + m * 16 + r) * N_ITEMS + ccol + n * 16] = acc[m][n][r];
}

// ---------------- rect fallback: fp16 MFMA sim GEMM -> fp16 sim (stripe-local rows) ----------------
__global__ __launch_bounds__(256) void sim_mfma_rect_k(const unsigned short* __restrict__ Zh,
                                                       unsigned short* __restrict__ C, int K, int r0) {
  __shared__ unsigned short smA[128 * 32];
  __shared__ unsigned short smB[128 * 32];
  const int tid = threadIdx.x;
  const int lane = tid & 63;
  const int wid = tid >> 6;
  const int wr = wid >> 1, wc = wid & 1;
  const int tileX = blockIdx.x, tileY = blockIdx.y;

  const int bRow = r0 + tileY * 128;
  const int bCol = tileX * 128;

  f32x4 acc[4][4];
  const f32x4 fzero = {0.f, 0.f, 0.f, 0.f};
  #pragma unroll
  for (int m = 0; m < 4; m++)
    #pragma unroll
    for (int n = 0; n < 4; n++) acc[m][n] = fzero;

  const int u0 = (wid * 2 + 0) * 64 + lane;
  const int u1 = (wid * 2 + 1) * 64 + lane;
  const int ar0 = u0 >> 2, ac0 = (u0 & 3) * 8;
  const int ar1 = u1 >> 2, ac1 = (u1 & 3) * 8;
  const size_t rowA0 = (size_t)(bRow + ar0) * K;
  const size_t rowA1 = (size_t)(bRow + ar1) * K;
  const size_t rowB0 = (size_t)(bCol + ar0) * K;
  const size_t rowB1 = (size_t)(bCol + ar1) * K;
  unsigned short* ldsA0 = smA + (wid * 2 + 0) * 512;
  unsigned short* ldsA1 = smA + (wid * 2 + 1) * 512;
  unsigned short* ldsB0 = smB + (wid * 2 + 0) * 512;
  unsigned short* ldsB1 = smB + (wid * 2 + 1) * 512;

  const int kc = lane >> 4;
  const int fr = lane & 15;

  for (int k0 = 0; k0 < K; k0 += 32) {
    __syncthreads();
    gld16(Zh + rowA0 + k0 + ac0, ldsA0);
    gld16(Zh + rowA1 + k0 + ac1, ldsA1);
    gld16(Zh + rowB0 + k0 + ac0, ldsB0);
    gld16(Zh + rowB1 + k0 + ac1, ldsB1);
    __syncthreads();

    f16x8 a[4], b[4];
    #pragma unroll
    for (int m = 0; m < 4; m++)
      a[m] = *(const f16x8*)&smA[(wr * 64 + m * 16 + fr) * 32 + kc * 8];
    #pragma unroll
    for (int n = 0; n < 4; n++)
      b[n] = *(const f16x8*)&smB[(wc * 64 + n * 16 + fr) * 32 + kc * 8];
    #pragma unroll
    for (int m = 0; m < 4; m++)
      #pragma unroll
      for (int n = 0; n < 4; n++)
        acc[m][n] = __builtin_amdgcn_mfma_f32_16x16x32_f16(a[m], b[n], acc[m][n], 0, 0, 0);
  }

  const int crow = tileY * 128 + wr * 64 + (lane >> 4) * 4;   // stripe-local rows
  const int ccol = bCol + wc * 64 + (lane & 15);
  #pragma unroll
  for (int m = 0; m < 4; m++)
    #pragma unroll
    for (int n = 0; n < 4; n++)
      #pragma unroll
      for (int r = 0; r < 4; r++)
        C[(size_t)(crow + m * 16 + r) * N_ITEMS + ccol + n * 16] = f2h(acc[m][n][r]);
}

// ---------------- convert fp32 tri tile -> fp16 direct + fp16 mirrored tile ----------------
__global__ __launch_bounds__(256) void conv_mirror_k(const float* __restrict__ Cf,
                                                     unsigned short* __restrict__ Ch,
                                                     const int* __restrict__ tile_map) {
  __shared__ unsigned short t[128 * LDS_ST];   // 33 KB, stride 129 breaks bank conflicts
  int tm = tile_map[blockIdx.x];
  const int ty = tm >> 16;
  const int tx = tm & 0xffff;
  const int tid = threadIdx.x;

  // pass 1: read fp32 rows (coalesced), convert, write fp16 direct tile, stash in LDS
  #pragma unroll
  for (int it = 0; it < 8; it++) {
    int idx = it * 2048 + tid * 8;
    int r = idx >> 7, c = idx & 127;
    const float* src = &Cf[(size_t)(ty * 128 + r) * N_ITEMS + tx * 128 + c];
    float4 v0 = *(const float4*)(src);
    float4 v1 = *(const float4*)(src + 4);
    unsigned short buf[8];
    buf[0] = f2h(v0.x); buf[1] = f2h(v0.y); buf[2] = f2h(v0.z); buf[3] = f2h(v0.w);
    buf[4] = f2h(v1.x); buf[5] = f2h(v1.y); buf[6] = f2h(v1.z); buf[7] = f2h(v1.w);
    *(uint4*)&Ch[(size_t)(ty * 128 + r) * N_ITEMS + tx * 128 + c] = *(const uint4*)buf;
    #pragma unroll
    for (int j = 0; j < 8; j++) t[r * LDS_ST + c + j] = buf[j];
  }
  if (tx == ty) return;        // uniform branch: diagonal tile needs no mirror
  __syncthreads();

  // pass 2: transposed gather from LDS -> coalesced fp16 store of mirrored tile
  #pragma unroll
  for (int it = 0; it < 8; it++) {
    int idx = it * 2048 + tid * 8;
    int orow = idx >> 7;      // source col
    int ocol = idx & 127;     // source row base
    unsigned short buf[8];
    #pragma unroll
    for (int j = 0; j < 8; j++) buf[j] = t[(ocol + j) * LDS_ST + orow];
    *(uint4*)&Ch[(size_t)(tx * 128 + orow) * N_ITEMS + ty * 128 + ocol] = *(const uint4*)buf;
  }
}

// ---------------- per-lane sorted-4 insertion ----------------
__device__ __forceinline__ void ins4(float val, int idx, float tv[4], int ti[4]) {
  if (beats(val, idx, tv[3], ti[3])) {
    tv[3] = val; ti[3] = idx;
    if (beats(tv[3], ti[3], tv[2], ti[2])) { float a=tv[2];int b=ti[2]; tv[2]=tv[3];ti[2]=ti[3]; tv[3]=a;ti[3]=b; }
    if (beats(tv[2], ti[2], tv[1], ti[1])) { float a=tv[1];int b=ti[1]; tv[1]=tv[2];ti[1]=ti[2]; tv[2]=a;ti[2]=b; }
    if (beats(tv[1], ti[1], tv[0], ti[0])) { float a=tv[0];int b=ti[0]; tv[0]=tv[1];ti[0]=ti[1]; tv[1]=a;ti[1]=b; }
  }
}

// ---------------- top-16 candidates per row from fp16 sim (wave per row) ----------------
__global__ __launch_bounds__(256) void topk16h_k(const unsigned short* __restrict__ sim,
                                                 int r0, int* __restrict__ cand) {
  int row = blockIdx.x * 4 + (threadIdx.x >> 6);   // stripe-local
  int lane = threadIdx.x & 63;
  const uint4* s8 = reinterpret_cast<const uint4*>(sim + (size_t)row * N_ITEMS);

  float tv[4]; int ti[4];
  #pragma unroll
  for (int k = 0; k < 4; k++) { tv[k] = -INFINITY; ti[k] = 0x7fffffff; }
  unsigned long long ext0 = 0ull, ext1 = 0ull;

  for (int i = 0; i < 16; i++) {
    uint4 v = s8[i * 64 + lane];
    int base = (i * 64 + lane) * 8;
    ins4(h2f(v.x & 0xffff), base + 0, tv, ti);
    ins4(h2f(v.x >> 16),    base + 1, tv, ti);
    ins4(h2f(v.y & 0xffff), base + 2, tv, ti);
    ins4(h2f(v.y >> 16),    base + 3, tv, ti);
    ins4(h2f(v.z & 0xffff), base + 4, tv, ti);
    ins4(h2f(v.z >> 16),    base + 5, tv, ti);
    ins4(h2f(v.w & 0xffff), base + 6, tv, ti);
    ins4(h2f(v.w >> 16),    base + 7, tv, ti);
  }
  int nvalid = 4;
  for (int t = 0; t < N_CAND; t++) {
    float bv = tv[0]; int bi = ti[0];
    for (int o = 32; o; o >>= 1) {
      float ov = __shfl_xor(bv, o, 64);
      int   oi = __shfl_xor(bi, o, 64);
      if (beats(ov, oi, bv, bi)) { bv = ov; bi = oi; }
    }
    if (tv[0] == bv && ti[0] == bi) {   // unique winner lane (indices unique)
      int slot = ((bi >> 9) << 3) | (bi & 7);   // i*8+q in [0,128)
      if (slot < 64) ext0 |= 1ull << slot; else ext1 |= 1ull << (slot - 64);
      tv[0]=tv[1];ti[0]=ti[1]; tv[1]=tv[2];ti[1]=ti[2]; tv[2]=tv[3];ti[2]=ti[3];
      tv[3]=-INFINITY; ti[3]=0x7fffffff;
      nvalid--;
      if (nvalid == 0) {   // exact refill from remaining elements
        for (int i = 0; i < 16; i++) {
          uint4 v = s8[i * 64 + lane];
          int base = (i * 64 + lane) * 8;
          float vv[8] = {h2f(v.x & 0xffff), h2f(v.x >> 16), h2f(v.y & 0xffff), h2f(v.y >> 16),
                         h2f(v.z & 0xffff), h2f(v.z >> 16), h2f(v.w & 0xffff), h2f(v.w >> 16)};
          #pragma unroll
          for (int q = 0; q < 8; q++) {
            int slot2 = i * 8 + q;
            bool used = (slot2 < 64) ? ((ext0 >> slot2) & 1ull) : ((ext1 >> (slot2 - 64)) & 1ull);
            if (!used) ins4(vv[q], base + q, tv, ti);
          }
        }
        nvalid = 4;
      }
    }
    if (lane == 0) cand[(size_t)(r0 + row) * N_CAND + t] = bi;
  }
}

// ---------------- fp32 exact refine: recompute 16 dots, take top-10 ----------------
__global__ __launch_bounds__(256) void refine_k(const float* __restrict__ X, int K,
                                                const float* __restrict__ invn,
                                                const int* __restrict__ cand,
                                                float* __restrict__ vals, int* __restrict__ inds,
                                                float* __restrict__ dis) {
  __shared__ __align__(16) float xr[4096];
  __shared__ float dots[N_CAND];
  int row = blockIdx.x;
  int tid = threadIdx.x, lane = tid & 63, wid = tid >> 6;
  for (int j = tid; j < K; j += 256) xr[j] = X[(size_t)row * K + j];
  __syncthreads();
  for (int c = wid; c < N_CAND; c += 4) {
    int ci = cand[(size_t)row * N_CAND + c];
    const float* xc = X + (size_t)ci * K;
    float p = 0.f;
    if (K == 4096) {
      const float4* xc4 = reinterpret_cast<const float4*>(xc);
      const float4* xr4 = reinterpret_cast<const float4*>(xr);
      for (int it = 0; it < 16; it++) {
        float4 a = xr4[it * 64 + lane];
        float4 g = xc4[it * 64 + lane];
        p += a.x * g.x + a.y * g.y + a.z * g.z + a.w * g.w;
      }
    } else {
      for (int j = lane; j < K; j += 64) p += xr[j] * xc[j];
    }
    for (int o = 32; o; o >>= 1) p += __shfl_xor(p, o, 64);
    if (lane == 0) dots[c] = p;
  }
  __syncthreads();
  if (tid == 0) {
    float v[N_CAND]; int id[N_CAND];
    float ir = invn[row];
    for (int c = 0; c < N_CAND; c++) {
      id[c] = cand[(size_t)row * N_CAND + c];
      v[c] = dots[c] * ir * invn[id[c]];
    }
    for (int a = 1; a < N_CAND; a++) {   // insertion sort: val desc, idx asc
      float av = v[a]; int ai = id[a];
      int b = a - 1;
      while (b >= 0 && beats(av, ai, v[b], id[b])) { v[b+1]=v[b]; id[b+1]=id[b]; b--; }
      v[b+1] = av; id[b+1] = ai;
    }
    float sum = 0.f;
    for (int t = 0; t < K_TOP; t++) {
      vals[(size_t)row * K_TOP + t] = v[t];
      inds[(size_t)row * K_TOP + t] = id[t];
      sum += v[t];
    }
    float rs = sum > 0.f ? sum : 1.0f;
    dis[row] = 1.0f / sqrtf(rs);
  }
}

// ---------------- vals *= dis[i] * dis[inds] ----------------
__global__ __launch_bounds__(256) void scale_vals_k(float* __restrict__ vals,
                                                    const int* __restrict__ inds,
                                                    const float* __restrict__ dis, int tot) {
  int idx = blockIdx.x * 256 + threadIdx.x;
  if (idx < tot) {
    int i = idx / K_TOP;
    vals[idx] *= dis[i] * dis[inds[idx]];
  }
}

// ---------------- fused row L2-norm + fp16 cast ----------------
__global__ __launch_bounds__(256) void norm_cast_fused_k(const float* __restrict__ x,
                                                         float* __restrict__ invn,
                                                         unsigned short* __restrict__ zh, int K) {
  __shared__ __align__(16) float xr[4096];
  __shared__ float red[256];
  int r = blockIdx.x;
  const float* xp = x + (size_t)r * K;
  float ss = 0.f;
  for (int j = threadIdx.x; j < K; j += 256) { float v = xp[j]; xr[j] = v; ss += v * v; }
  red[threadIdx.x] = ss; __syncthreads();
  for (int s = 128; s > 0; s >>= 1) {
    if (threadIdx.x < s) red[threadIdx.x] += red[threadIdx.x + s];
    __syncthreads();
  }
  float inv = 1.f / fmaxf(sqrtf(red[0]), 1e-12f);
  if (threadIdx.x == 0) invn[r] = inv;
  for (int j = threadIdx.x; j < K; j += 256) {
    zh[(size_t)r * K + j] = f2h(xr[j] * inv);
  }
}

// ---------------- split-K register-tiled fp32 linear: out += X @ W (+b on split 0) ----------------
__global__ __launch_bounds__(256) void linear_splitk_k(const float* __restrict__ X,
                                                       const float* __restrict__ W,
                                                       const float* __restrict__ b,
                                                       float* __restrict__ outp, int K, int KS) {
  __shared__ float As[64][17];
  __shared__ float Ws[16][64];
  int br = blockIdx.x, ks = blockIdx.y;
  int tid = threadIdx.x, tr = tid >> 4, tc = tid & 15;
  int k0 = ks * KS, k1 = k0 + KS;
  int lrow = tid >> 2, lk = (tid & 3) * 4;
  int wrow = tid >> 4, wcol = (tid & 15) * 4;
  float acc[4][4] = {};
  for (int kb = k0; kb < k1; kb += 16) {
    __syncthreads();
    float4 xv = *(const float4*)&X[(size_t)(br * 64 + lrow) * K + kb + lk];
    As[lrow][lk + 0] = xv.x; As[lrow][lk + 1] = xv.y;
    As[lrow][lk + 2] = xv.z; As[lrow][lk + 3] = xv.w;
    *(float4*)&Ws[wrow][wcol] = *(const float4*)&W[(size_t)(kb + wrow) * 64 + wcol];
    __syncthreads();
    #pragma unroll
    for (int k = 0; k < 16; k++) {
      float a[4], w[4];
      #pragma unroll
      for (int i = 0; i < 4; i++) a[i] = As[tr * 4 + i][k];
      #pragma unroll
      for (int j = 0; j < 4; j++) w[j] = Ws[k][tc * 4 + j];
      #pragma unroll
      for (int i = 0; i < 4; i++)
        #pragma unroll
        for (int j = 0; j < 4; j++) acc[i][j] += a[i] * w[j];
    }
  }
  #pragma unroll
  for (int i = 0; i < 4; i++)
    #pragma unroll
    for (int j = 0; j < 4; j++) {
      float v = acc[i][j];
      if (ks == 0) v += b[tc * 4 + j];
      atomicAdd(&outp[(size_t)(br * 64 + tr * 4 + i) * 64 + tc * 4 + j], v);
    }
}

// ---------------- fused knn_mm pair ----------------
__global__ __launch_bounds__(256) void fuse_knn_k(const float* __restrict__ av, const int* __restrict__ ai,
                                                  const float* __restrict__ bv, const int* __restrict__ bi_,
                                                  const float* __restrict__ e, float* __restrict__ outp,
                                                  float lam) {
  int i = blockIdx.x * 4 + (threadIdx.x >> 6), d = threadIdx.x & 63;
  float sa = 0.f, sb = 0.f;
  #pragma unroll
  for (int k = 0; k < K_TOP; k++) {
    sa += av[(size_t)i * K_TOP + k] * e[(size_t)ai[(size_t)i * K_TOP + k] * 64 + d];
    sb += bv[(size_t)i * K_TOP + k] * e[(size_t)bi_[(size_t)i * K_TOP + k] * 64 + d];
  }
  outp[(size_t)i * 64 + d] = (1.f - lam) * sa + lam * sb;
}

// ---------------- attention + h ----------------
__global__ __launch_bounds__(64) void attn_k(const float* __restrict__ img_e, const float* __restrict__ txt_e,
                                             const float* __restrict__ qw1, const float* __restrict__ qb1,
                                             const float* __restrict__ qw2, float* __restrict__ h) {
  __shared__ float W1[64][64];
  __shared__ float sI[64], sT[64];
  int t = threadIdx.x; int i = blockIdx.x;
  for (int k = 0; k < 64; k++) W1[k][t] = qw1[k * 64 + t];
  sI[t] = img_e[(size_t)i * 64 + t];
  sT[t] = txt_e[(size_t)i * 64 + t];
  __syncthreads();
  float yi = qb1[t], yt = qb1[t];
  #pragma unroll 16
  for (int k = 0; k < 64; k++) { yi += sI[k] * W1[k][t]; yt += sT[k] * W1[k][t]; }
  float w2 = qw2[t];
  float pi = tanhf(yi) * w2, pt = tanhf(yt) * w2;
  for (int o = 32; o > 0; o >>= 1) { pi += __shfl_xor(pi, o, 64); pt += __shfl_xor(pt, o, 64); }
  float m = fmaxf(pi, pt);
  float ei = expf(pi - m), et = expf(pt - m);
  float den = ei + et;
  float w0 = ei / den, w1v = et / den;
  h[(size_t)i * 64 + t] = w0 * sI[t] + w1v * sT[t];
}

// ---------------- CSR build: histogram ----------------
__global__ __launch_bounds__(256) void hist_k(const int* __restrict__ rows, int* __restrict__ cnt) {
  int e = blockIdx.x * 256 + threadIdx.x;
  if (e < NNZ_E) atomicAdd(&cnt[rows[e]], 1);
}

// ---------------- CSR build: exclusive scan over 24576 bins (1 block) ----------------
__global__ __launch_bounds__(256) void scan_k(const int* __restrict__ cnt,
                                              int* __restrict__ starts,
                                              int* __restrict__ cursor) {
  __shared__ int part[256];
  int t = threadIdx.x;
  int base = t * (N_TOTAL / 256);
  int s = 0;
  for (int j = 0; j < N_TOTAL / 256; j++) s += cnt[base + j];
  part[t] = s;
  __syncthreads();
  for (int off = 1; off < 256; off <<= 1) {
    int v = part[t];
    int u = (t >= off) ? part[t - off] : 0;
    __syncthreads();
    part[t] = v + u;
    __syncthreads();
  }
  int run = (t > 0) ? part[t - 1] : 0;
  for (int j = 0; j < N_TOTAL / 256; j++) {
    starts[base + j] = run;
    cursor[base + j] = run;
    run += cnt[base + j];
  }
  if (t == 255) starts[N_TOTAL] = run;
}

// ---------------- CSR build: place edges, pre-gathering cols/vals into CSR order ----------------
__global__ __launch_bounds__(256) void place_k(const int* __restrict__ rows,
                                               const int* __restrict__ cols,
                                               const float* __restrict__ vals,
                                               int* __restrict__ cursor,
                                               int* __restrict__ cols_s,
                                               float* __restrict__ vals_s) {
  int e = blockIdx.x * 256 + threadIdx.x;
  if (e < NNZ_E) {
    int p = atomicAdd(&cursor[rows[e]], 1);
    cols_s[p] = cols[e];
    vals_s[p] = vals[e];
  }
}

// ---------------- CSR gather segment_sum: wave per row ----------------
__global__ __launch_bounds__(256) void gather_gcn_k(const int* __restrict__ starts,
                                                    const int* __restrict__ cols_s,
                                                    const float* __restrict__ vals_s,
                                                    const float* __restrict__ ego,
                                                    float* __restrict__ side) {
  int row = blockIdx.x * 4 + (threadIdx.x >> 6);
  int d = threadIdx.x & 63;
  int s = starts[row], e = starts[row + 1];
  float acc = 0.f;
  for (int i = s; i < e; i++) {
    acc += vals_s[i] * ego[(size_t)cols_s[i] * 64 + d];
  }
  side[(size_t)row * 64 + d] = acc;
}

// ---------------- GCN layer ----------------
__global__ __launch_bounds__(256) void gcn_k(const float* __restrict__ side, const float* __restrict__ ego,
                                             const float* __restrict__ gw, const float* __restrict__ gb,
                                             const float* __restrict__ bw, const float* __restrict__ bb,
                                             float* __restrict__ outp) {
  __shared__ float W1[64][64], W2[64][64];
  __shared__ float S[4][64], E[4][64];
  int t = threadIdx.x & 63, rb = threadIdx.x >> 6;
  int r = blockIdx.x * 4 + rb;
  for (int idx = threadIdx.x; idx < 4096; idx += 256) {
    W1[idx >> 6][idx & 63] = gw[idx];
    W2[idx >> 6][idx & 63] = bw[idx];
  }
  S[rb][t] = side[(size_t)r * 64 + t];
  E[rb][t] = ego[(size_t)r * 64 + t];
  __syncthreads();
  float s = gb[t], b = bb[t];
  #pragma unroll 16
  for (int k = 0; k < 64; k++) {
    float sv = S[rb][k];
    s += sv * W1[k][t];
    b += E[rb][k] * sv * W2[k][t];
  }
  outp[(size_t)r * 64 + t] = leaky01(s) + leaky01(b);
}

// ---------------- acc += l2norm(ego) rowwise ----------------
__global__ __launch_bounds__(256) void l2acc_k(const float* __restrict__ ego, float* __restrict__ acc) {
  int r = blockIdx.x * 4 + (threadIdx.x >> 6), d = threadIdx.x & 63;
  float v = ego[(size_t)r * 64 + d];
  float ss = v * v;
  for (int o = 32; o > 0; o >>= 1) ss += __shfl_xor(ss, o, 64);
  float inv = 1.f / fmaxf(sqrtf(ss), 1e-12f);
  acc[(size_t)r * 64 + d] += v * inv;
}

// ---------------- init ego/acc ----------------
__global__ __launch_bounds__(256) void init_ego_k(const float* __restrict__ ue, const float* __restrict__ ie,
                                                  float* __restrict__ ego, float* __restrict__ acc) {
  int r = blockIdx.x * 4 + (threadIdx.x >> 6), d = threadIdx.x & 63;
  float v = (r < N_USERS) ? ue[(size_t)r * 64 + d] : ie[(size_t)(r - N_USERS) * 64 + d];
  ego[(size_t)r * 64 + d] = v;
  acc[(size_t)r * 64 + d] = v;
}

// ---------------- final outputs ----------------
__global__ __launch_bounds__(256) void final_k(const float* __restrict__ acc, const float* __restrict__ h,
                                               float* __restrict__ u_g, float* __restrict__ i_g) {
  int r = blockIdx.x * 4 + (threadIdx.x >> 6), d = threadIdx.x & 63;
  float m = acc[(size_t)r * 64 + d] * (1.0f / 3.0f);
  if (r < N_USERS) {
    u_g[(size_t)r * 64 + d] = m;
  } else {
    int i = r - N_USERS;
    float hv = h[(size_t)i * 64 + d];
    float ss = hv * hv;
    for (int o = 32; o > 0; o >>= 1) ss += __shfl_xor(ss, o, 64);
    float inv = 1.f / fmaxf(sqrtf(ss), 1e-12f);
    i_g[(size_t)i * 64 + d] = m + hv * inv;
  }
}

// ---------------- host-side graph builder ----------------
static void build_graph(hipStream_t stream, const float* feats, int K, float* invn,
                        unsigned short* zh, unsigned short* simh, float* simf,
                        int tri_ok, int stripe, int* cand, const int* tile_map,
                        float* vals, int* inds, float* dis) {
  norm_cast_fused_k<<<N_ITEMS, 256, 0, stream>>>(feats, invn, zh, K);
  if (tri_ok) {
    sim_mfma_tri_k<<<TRI_BLOCKS, 256, 0, stream>>>(zh, simf, K, tile_map);
    conv_mirror_k<<<TRI_BLOCKS, 256, 0, stream>>>(simf, simh, tile_map);
    topk16h_k<<<N_ITEMS / 4, 256, 0, stream>>>(simh, 0, cand);
  } else {
    for (int r0 = 0; r0 < N_ITEMS; r0 += stripe) {
      int rows = (N_ITEMS - r0) < stripe ? (N_ITEMS - r0) : stripe;
      dim3 g(N_ITEMS / 128, rows / 128);
      sim_mfma_rect_k<<<g, 256, 0, stream>>>(zh, simh, K, r0);
      topk16h_k<<<rows / 4, 256, 0, stream>>>(simh, r0, cand);
    }
  }
  refine_k<<<N_ITEMS, 256, 0, stream>>>(feats, K, invn, cand, vals, inds, dis);
  int tot = N_ITEMS * K_TOP;
  scale_vals_k<<<(tot + 255) / 256, 256, 0, stream>>>(vals, inds, dis, tot);
}

extern "C" void kernel_launch(void* const* d_in, const int* in_sizes, int n_in,
                              void* d_out, int out_size, void* d_ws, size_t ws_size,
                              hipStream_t stream) {
  const int*   adj_rows   = (const int*)d_in[0];
  const int*   adj_cols   = (const int*)d_in[1];
  const float* adj_vals   = (const float*)d_in[2];
  const float* image_feats= (const float*)d_in[3];
  const float* text_feats = (const float*)d_in[4];
  const float* user_emb   = (const float*)d_in[5];
  const float* item_emb   = (const float*)d_in[6];
  const float* img_w      = (const float*)d_in[7];
  const float* img_b      = (const float*)d_in[8];
  const float* txt_w      = (const float*)d_in[9];
  const float* txt_b      = (const float*)d_in[10];
  const float* q_w1       = (const float*)d_in[11];
  const float* q_b1       = (const float*)d_in[12];
  const float* q_w2       = (const float*)d_in[13];
  const float* gc_w       = (const float*)d_in[14];
  const float* gc_b       = (const float*)d_in[15];
  const float* bi_w       = (const float*)d_in[16];
  const float* bi_b       = (const float*)d_in[17];

  float* out  = (float*)d_out;
  float* u_g  = out;
  float* i_g  = u_g + (size_t)N_USERS * 64;
  float* imgE = i_g + (size_t)N_ITEMS * 64;
  float* txtE = imgE + (size_t)N_ITEMS * 64;
  float* hOut = txtE + (size_t)N_ITEMS * 64;

  // ---- workspace layout (floats) ----
  float* W = (float*)d_ws;
  size_t off = 0;
  auto alloc = [&](size_t n) { float* q = W + off; off += n; return q; };
  float* inv_io = alloc(N_ITEMS);
  float* inv_to = alloc(N_ITEMS);
  float* inv_in = alloc(N_ITEMS);
  float* inv_tn = alloc(N_ITEMS);
  float* img_f  = alloc((size_t)N_ITEMS * 64);
  float* txt_f  = alloc((size_t)N_ITEMS * 64);
  float* vals0 = alloc(N_ITEMS * K_TOP); int* inds0 = (int*)alloc(N_ITEMS * K_TOP);
  float* vals1 = alloc(N_ITEMS * K_TOP); int* inds1 = (int*)alloc(N_ITEMS * K_TOP);
  float* vals2 = alloc(N_ITEMS * K_TOP); int* inds2 = (int*)alloc(N_ITEMS * K_TOP);
  float* vals3 = alloc(N_ITEMS * K_TOP); int* inds3 = (int*)alloc(N_ITEMS * K_TOP);
  float* dis0 = alloc(N_ITEMS);
  float* dis1 = alloc(N_ITEMS);
  float* dis2 = alloc(N_ITEMS);
  float* dis3 = alloc(N_ITEMS);
  int*   cand = (int*)alloc((size_t)N_ITEMS * N_CAND);
  int*   tile_map = (int*)alloc(TRI_BLOCKS);
  float* ego_a = alloc((size_t)N_TOTAL * 64);
  float* ego_b = alloc((size_t)N_TOTAL * 64);
  float* side  = alloc((size_t)N_TOTAL * 64);
  float* acc   = alloc((size_t)N_TOTAL * 64);
  int* csr_cnt    = (int*)alloc(N_TOTAL);
  int* csr_starts = (int*)alloc(N_TOTAL + 1);
  int* csr_cursor = (int*)alloc(N_TOTAL);
  int* csr_cols   = (int*)alloc(NNZ_E);
  float* csr_vals = alloc(NNZ_E);
  unsigned short* zh = (unsigned short*)alloc(((size_t)N_ITEMS * IMG_DIM) / 2);  // 64MB fp16

  const size_t simh_b = (size_t)N_ITEMS * N_ITEMS * 2;   // 128MB fp16
  const size_t simf_b = (size_t)N_ITEMS * N_ITEMS * 4;   // 256MB fp32
  size_t used_bytes = off * 4;
  size_t avail_b = (ws_size > used_bytes) ? (ws_size - used_bytes) : 0;
  unsigned short* simh = (unsigned short*)(W + off);
  float* simf = (float*)((char*)simh + simh_b);
  int tri_ok = (avail_b >= simh_b + simf_b);

  int stripe = N_ITEMS;
  if (!tri_ok) {
    long stripe_l = (long)((avail_b / ((size_t)N_ITEMS * 2)) / 128) * 128;
    if (stripe_l > N_ITEMS) stripe_l = N_ITEMS;
    if (stripe_l < 128) stripe_l = 128;
    stripe = (int)stripe_l;
  }

  // ---- one-time tables ----
  fill_map_k<<<(TRI_BLOCKS + 255) / 256, 256, 0, stream>>>(tile_map);

  // ---- CSR build (once, reused by both GCN layers) ----
  hipMemsetAsync(csr_cnt, 0, N_TOTAL * sizeof(int), stream);
  hist_k<<<(NNZ_E + 255) / 256, 256, 0, stream>>>(adj_rows, csr_cnt);
  scan_k<<<1, 256, 0, stream>>>(csr_cnt, csr_starts, csr_cursor);
  place_k<<<(NNZ_E + 255) / 256, 256, 0, stream>>>(adj_rows, adj_cols, adj_vals,
                                                   csr_cursor, csr_cols, csr_vals);

  // ---- 4 KNN graphs ----
  build_graph(stream, image_feats, IMG_DIM, inv_io, zh, simh, simf, tri_ok, stripe, cand, tile_map, vals0, inds0, dis0);
  build_graph(stream, text_feats,  TXT_DIM, inv_to, zh, simh, simf, tri_ok, stripe, cand, tile_map, vals1, inds1, dis1);

  hipMemsetAsync(img_f, 0, (size_t)N_ITEMS * 64 * sizeof(float), stream);
  hipMemsetAsync(txt_f, 0, (size_t)N_ITEMS * 64 * sizeof(float), stream);
  linear_splitk_k<<<dim3(N_ITEMS / 64, 4), 256, 0, stream>>>(image_feats, img_w, img_b, img_f, IMG_DIM, IMG_DIM / 4);
  linear_splitk_k<<<dim3(N_ITEMS / 64, 4), 256, 0, stream>>>(text_feats,  txt_w, txt_b, txt_f, TXT_DIM, TXT_DIM / 4);

  build_graph(stream, img_f, 64, inv_in, zh, simh, simf, tri_ok, stripe, cand, tile_map, vals2, inds2, dis2);
  build_graph(stream, txt_f, 64, inv_tn, zh, simh, simf, tri_ok, stripe, cand, tile_map, vals3, inds3, dis3);

  // ---- img_e / txt_e ----
  const float lam = 0.9f;
  fuse_knn_k<<<N_ITEMS / 4, 256, 0, stream>>>(vals2, inds2, vals0, inds0, item_emb, imgE, lam);
  fuse_knn_k<<<N_ITEMS / 4, 256, 0, stream>>>(vals3, inds3, vals1, inds1, item_emb, txtE, lam);

  // ---- attention + h ----
  attn_k<<<N_ITEMS, 64, 0, stream>>>(imgE, txtE, q_w1, q_b1, q_w2, hOut);

  // ---- GCN ----
  init_ego_k<<<N_TOTAL / 4, 256, 0, stream>>>(user_emb, item_emb, ego_a, acc);

  // layer 0
  gather_gcn_k<<<N_TOTAL / 4, 256, 0, stream>>>(csr_starts, csr_cols, csr_vals, ego_a, side);
  gcn_k<<<N_TOTAL / 4, 256, 0, stream>>>(side, ego_a, gc_w, gc_b, bi_w, bi_b, ego_b);
  l2acc_k<<<N_TOTAL / 4, 256, 0, stream>>>(ego_b, acc);

  // layer 1
  gather_gcn_k<<<N_TOTAL / 4, 256, 0, stream>>>(csr_starts, csr_cols, csr_vals, ego_b, side);
  gcn_k<<<N_TOTAL / 4, 256, 0, stream>>>(side, ego_b, gc_w + 4096, gc_b + 64, bi_w + 4096, bi_b + 64, ego_a);
  l2acc_k<<<N_TOTAL / 4, 256, 0, stream>>>(ego_a, acc);

  // ---- final outputs ----
  final_k<<<N_TOTAL / 4, 256, 0, stream>>>(acc, hOut, u_g, i_g);
}

// Round 16
// 2405.346 us; speedup vs baseline: 1.0847x; 1.0847x over previous
//
#include <hip/hip_runtime.h>
#include <hip/hip_bf16.h>
#include <math.h>

#define N_USERS 16384
#define N_ITEMS 8192
#define N_TOTAL 24576
#define EMB_D 64
#define IMG_DIM 4096
#define TXT_DIM 384
#define K_TOP 10
#define N_CAND 16
#define NNZ_E 786432
#define NTILE 64                 // N_ITEMS / 128
#define TRI_BLOCKS (NTILE * (NTILE + 1) / 2)   // 2080
#define MIR_BLOCKS (NTILE * (NTILE - 1) / 2)   // 2016
#define LDS_ST 129

typedef _Float16 f16x8 __attribute__((ext_vector_type(8)));
typedef float f32x4 __attribute__((ext_vector_type(4)));

#define AS1 __attribute__((address_space(1)))
#define AS3 __attribute__((address_space(3)))

__device__ __forceinline__ float leaky01(float x){ return x >= 0.f ? x : 0.01f * x; }

__device__ __forceinline__ void gld16(const void* g, void* l) {
  __builtin_amdgcn_global_load_lds((const AS1 unsigned int*)g, (AS3 unsigned int*)l, 16, 0, 0);
}

__device__ __forceinline__ bool beats(float v, int i, float u, int j) {
  return v > u || (v == u && i < j);
}

__device__ __forceinline__ float h2f(unsigned short u) {
  _Float16 h = __builtin_bit_cast(_Float16, u);
  return (float)h;
}
__device__ __forceinline__ unsigned short f2h(float v) {
  _Float16 h = (_Float16)v;
  return __builtin_bit_cast(unsigned short, h);
}

// ---------------- fill supertile tile map (once; reused by all graphs) ----------------
__global__ __launch_bounds__(256) void fill_map_k(int* __restrict__ map) {
  int b = blockIdx.x * 256 + threadIdx.x;
  if (b >= TRI_BLOCKS) return;
  int tileX, tileY;
  if (b < 1792) {               // 28 strict-upper supertiles, 64 tiles each
    int s = b >> 6, w = b & 63;
    int sy = 0, rem = 7;
    while (s >= rem) { s -= rem; sy++; rem--; }
    int sx = sy + 1 + s;
    tileY = sy * 8 + (w >> 3);
    tileX = sx * 8 + (w & 7);
  } else {                      // 8 diagonal supertiles, 36 tiles each
    int b2 = b - 1792;
    int sd = b2 / 36, w = b2 - sd * 36;
    int i = 0, rem = 8;
    while (w >= rem) { w -= rem; i++; rem--; }
    tileY = sd * 8 + i;
    tileX = sd * 8 + i + w;
  }
  map[b] = (tileY << 16) | tileX;
}

// ---------------- fp16 MFMA sim GEMM -> fp16 sim (r14 best-measured config) ----------------
// TRI=1: triangular grid via precomputed tile_map; mirror done by tri_mirror_k.
// TRI=0: rectangular stripe grid (stripe-local rows).
template<int TRI>
__global__ __launch_bounds__(256) void sim_mfma_k(const unsigned short* __restrict__ Zh,
                                                  unsigned short* __restrict__ C, int K, int r0,
                                                  const int* __restrict__ tile_map) {
  __shared__ unsigned short smA[128 * 32];
  __shared__ unsigned short smB[128 * 32];
  const int tid = threadIdx.x;
  const int lane = tid & 63;
  const int wid = tid >> 6;
  const int wr = wid >> 1, wc = wid & 1;

  int tileX, tileY;
  if (TRI) {
    int tm = tile_map[blockIdx.x];   // uniform -> scalar load
    tileY = tm >> 16;
    tileX = tm & 0xffff;
  } else {
    tileX = blockIdx.x; tileY = blockIdx.y;
  }

  const int bRow = r0 + tileY * 128;
  const int bCol = tileX * 128;

  f32x4 acc[4][4];
  const f32x4 fzero = {0.f, 0.f, 0.f, 0.f};
  #pragma unroll
  for (int m = 0; m < 4; m++)
    #pragma unroll
    for (int n = 0; n < 4; n++) acc[m][n] = fzero;

  const int u0 = (wid * 2 + 0) * 64 + lane;
  const int u1 = (wid * 2 + 1) * 64 + lane;
  const int ar0 = u0 >> 2, ac0 = (u0 & 3) * 8;
  const int ar1 = u1 >> 2, ac1 = (u1 & 3) * 8;
  // 32-bit byte offsets (max 64MB < 4GB); rebuilt into 64-bit addr in-loop
  const unsigned offA0 = ((unsigned)(bRow + ar0) * (unsigned)K + (unsigned)ac0) * 2u;
  const unsigned offA1 = ((unsigned)(bRow + ar1) * (unsigned)K + (unsigned)ac1) * 2u;
  const unsigned offB0 = ((unsigned)(bCol + ar0) * (unsigned)K + (unsigned)ac0) * 2u;
  const unsigned offB1 = ((unsigned)(bCol + ar1) * (unsigned)K + (unsigned)ac1) * 2u;
  const char* Zb = (const char*)Zh;
  unsigned short* ldsA0 = smA + (wid * 2 + 0) * 512;
  unsigned short* ldsA1 = smA + (wid * 2 + 1) * 512;
  unsigned short* ldsB0 = smB + (wid * 2 + 0) * 512;
  unsigned short* ldsB1 = smB + (wid * 2 + 1) * 512;

  const int kc = lane >> 4;
  const int fr = lane & 15;

  for (unsigned kb = 0; kb < (unsigned)K * 2u; kb += 64u) {   // byte step = 32 elems * 2B
    __syncthreads();
    gld16(Zb + (offA0 + kb), ldsA0);
    gld16(Zb + (offA1 + kb), ldsA1);
    gld16(Zb + (offB0 + kb), ldsB0);
    gld16(Zb + (offB1 + kb), ldsB1);
    __syncthreads();

    f16x8 a[4], b[4];
    #pragma unroll
    for (int m = 0; m < 4; m++)
      a[m] = *(const f16x8*)&smA[(wr * 64 + m * 16 + fr) * 32 + kc * 8];
    #pragma unroll
    for (int n = 0; n < 4; n++)
      b[n] = *(const f16x8*)&smB[(wc * 64 + n * 16 + fr) * 32 + kc * 8];
    #pragma unroll
    for (int m = 0; m < 4; m++)
      #pragma unroll
      for (int n = 0; n < 4; n++)
        acc[m][n] = __builtin_amdgcn_mfma_f32_16x16x32_f16(a[m], b[n], acc[m][n], 0, 0, 0);
  }

  // direct write only: 2B scatter, 16 lanes -> 32B runs
  const int crow = tileY * 128 + wr * 64 + (lane >> 4) * 4;  // stripe-local rows in rect, global in tri
  const int ccol = bCol + wc * 64 + (lane & 15);
  #pragma unroll
  for (int m = 0; m < 4; m++)
    #pragma unroll
    for (int n = 0; n < 4; n++)
      #pragma unroll
      for (int r = 0; r < 4; r++)
        C[(size_t)(crow + m * 16 + r) * N_ITEMS + ccol + n * 16] = f2h(acc[m][n][r]);
}

// ---------------- mirror strict-upper tiles: C[x][y] = C[y][x] (LDS-staged transpose) ----------------
__global__ __launch_bounds__(256) void tri_mirror_k(unsigned short* __restrict__ C) {
  __shared__ unsigned short t[128 * LDS_ST];   // 33 KB, stride 129 breaks bank conflicts
  int b = blockIdx.x;
  int ty = 0, rem = NTILE - 1;
  while (b >= rem) { b -= rem; ty++; rem--; }
  int tx = ty + 1 + b;
  const int tid = threadIdx.x;

  #pragma unroll
  for (int it = 0; it < 8; it++) {
    int idx = it * 2048 + tid * 8;
    int r = idx >> 7, c = idx & 127;
    uint4 v = *(const uint4*)&C[(size_t)(ty * 128 + r) * N_ITEMS + tx * 128 + c];
    const unsigned short* pv = (const unsigned short*)&v;
    #pragma unroll
    for (int j = 0; j < 8; j++) t[r * LDS_ST + c + j] = pv[j];
  }
  __syncthreads();

  #pragma unroll
  for (int it = 0; it < 8; it++) {
    int idx = it * 2048 + tid * 8;
    int orow = idx >> 7;      // source col
    int ocol = idx & 127;     // source row base
    unsigned short buf[8];
    #pragma unroll
    for (int j = 0; j < 8; j++) buf[j] = t[(ocol + j) * LDS_ST + orow];
    *(uint4*)&C[(size_t)(tx * 128 + orow) * N_ITEMS + ty * 128 + ocol] = *(const uint4*)buf;
  }
}

// ---------------- per-lane sorted-4 insertion ----------------
__device__ __forceinline__ void ins4(float val, int idx, float tv[4], int ti[4]) {
  if (beats(val, idx, tv[3], ti[3])) {
    tv[3] = val; ti[3] = idx;
    if (beats(tv[3], ti[3], tv[2], ti[2])) { float a=tv[2];int b=ti[2]; tv[2]=tv[3];ti[2]=ti[3]; tv[3]=a;ti[3]=b; }
    if (beats(tv[2], ti[2], tv[1], ti[1])) { float a=tv[1];int b=ti[1]; tv[1]=tv[2];ti[1]=ti[2]; tv[2]=a;ti[2]=b; }
    if (beats(tv[1], ti[1], tv[0], ti[0])) { float a=tv[0];int b=ti[0]; tv[0]=tv[1];ti[0]=ti[1]; tv[1]=a;ti[1]=b; }
  }
}

// ---------------- top-16 candidates per row from fp16 sim (wave per row) ----------------
__global__ __launch_bounds__(256) void topk16h_k(const unsigned short* __restrict__ sim,
                                                 int r0, int* __restrict__ cand) {
  int row = blockIdx.x * 4 + (threadIdx.x >> 6);   // stripe-local
  int lane = threadIdx.x & 63;
  const uint4* s8 = reinterpret_cast<const uint4*>(sim + (size_t)row * N_ITEMS);

  float tv[4]; int ti[4];
  #pragma unroll
  for (int k = 0; k < 4; k++) { tv[k] = -INFINITY; ti[k] = 0x7fffffff; }
  unsigned long long ext0 = 0ull, ext1 = 0ull;

  for (int i = 0; i < 16; i++) {
    uint4 v = s8[i * 64 + lane];
    int base = (i * 64 + lane) * 8;
    ins4(h2f(v.x & 0xffff), base + 0, tv, ti);
    ins4(h2f(v.x >> 16),    base + 1, tv, ti);
    ins4(h2f(v.y & 0xffff), base + 2, tv, ti);
    ins4(h2f(v.y >> 16),    base + 3, tv, ti);
    ins4(h2f(v.z & 0xffff), base + 4, tv, ti);
    ins4(h2f(v.z >> 16),    base + 5, tv, ti);
    ins4(h2f(v.w & 0xffff), base + 6, tv, ti);
    ins4(h2f(v.w >> 16),    base + 7, tv, ti);
  }
  int nvalid = 4;
  for (int t = 0; t < N_CAND; t++) {
    float bv = tv[0]; int bi = ti[0];
    for (int o = 32; o; o >>= 1) {
      float ov = __shfl_xor(bv, o, 64);
      int   oi = __shfl_xor(bi, o, 64);
      if (beats(ov, oi, bv, bi)) { bv = ov; bi = oi; }
    }
    if (tv[0] == bv && ti[0] == bi) {   // unique winner lane (indices unique)
      int slot = ((bi >> 9) << 3) | (bi & 7);   // i*8+q in [0,128)
      if (slot < 64) ext0 |= 1ull << slot; else ext1 |= 1ull << (slot - 64);
      tv[0]=tv[1];ti[0]=ti[1]; tv[1]=tv[2];ti[1]=ti[2]; tv[2]=tv[3];ti[2]=ti[3];
      tv[3]=-INFINITY; ti[3]=0x7fffffff;
      nvalid--;
      if (nvalid == 0) {   // exact refill from remaining elements
        for (int i = 0; i < 16; i++) {
          uint4 v = s8[i * 64 + lane];
          int base = (i * 64 + lane) * 8;
          float vv[8] = {h2f(v.x & 0xffff), h2f(v.x >> 16), h2f(v.y & 0xffff), h2f(v.y >> 16),
                         h2f(v.z & 0xffff), h2f(v.z >> 16), h2f(v.w & 0xffff), h2f(v.w >> 16)};
          #pragma unroll
          for (int q = 0; q < 8; q++) {
            int slot2 = i * 8 + q;
            bool used = (slot2 < 64) ? ((ext0 >> slot2) & 1ull) : ((ext1 >> (slot2 - 64)) & 1ull);
            if (!used) ins4(vv[q], base + q, tv, ti);
          }
        }
        nvalid = 4;
      }
    }
    if (lane == 0) cand[(size_t)(r0 + row) * N_CAND + t] = bi;
  }
}

// ---------------- fp32 exact refine: recompute 16 dots, take top-10 ----------------
__global__ __launch_bounds__(256) void refine_k(const float* __restrict__ X, int K,
                                                const float* __restrict__ invn,
                                                const int* __restrict__ cand,
                                                float* __restrict__ vals, int* __restrict__ inds,
                                                float* __restrict__ dis) {
  __shared__ __align__(16) float xr[4096];
  __shared__ float dots[N_CAND];
  int row = blockIdx.x;
  int tid = threadIdx.x, lane = tid & 63, wid = tid >> 6;
  for (int j = tid; j < K; j += 256) xr[j] = X[(size_t)row * K + j];
  __syncthreads();
  for (int c = wid; c < N_CAND; c += 4) {
    int ci = cand[(size_t)row * N_CAND + c];
    const float* xc = X + (size_t)ci * K;
    float p = 0.f;
    if (K == 4096) {
      const float4* xc4 = reinterpret_cast<const float4*>(xc);
      const float4* xr4 = reinterpret_cast<const float4*>(xr);
      for (int it = 0; it < 16; it++) {
        float4 a = xr4[it * 64 + lane];
        float4 g = xc4[it * 64 + lane];
        p += a.x * g.x + a.y * g.y + a.z * g.z + a.w * g.w;
      }
    } else {
      for (int j = lane; j < K; j += 64) p += xr[j] * xc[j];
    }
    for (int o = 32; o; o >>= 1) p += __shfl_xor(p, o, 64);
    if (lane == 0) dots[c] = p;
  }
  __syncthreads();
  if (tid == 0) {
    float v[N_CAND]; int id[N_CAND];
    float ir = invn[row];
    for (int c = 0; c < N_CAND; c++) {
      id[c] = cand[(size_t)row * N_CAND + c];
      v[c] = dots[c] * ir * invn[id[c]];
    }
    for (int a = 1; a < N_CAND; a++) {   // insertion sort: val desc, idx asc
      float av = v[a]; int ai = id[a];
      int b = a - 1;
      while (b >= 0 && beats(av, ai, v[b], id[b])) { v[b+1]=v[b]; id[b+1]=id[b]; b--; }
      v[b+1] = av; id[b+1] = ai;
    }
    float sum = 0.f;
    for (int t = 0; t < K_TOP; t++) {
      vals[(size_t)row * K_TOP + t] = v[t];
      inds[(size_t)row * K_TOP + t] = id[t];
      sum += v[t];
    }
    float rs = sum > 0.f ? sum : 1.0f;
    dis[row] = 1.0f / sqrtf(rs);
  }
}

// ---------------- vals *= dis[i] * dis[inds] ----------------
__global__ __launch_bounds__(256) void scale_vals_k(float* __restrict__ vals,
                                                    const int* __restrict__ inds,
                                                    const float* __restrict__ dis, int tot) {
  int idx = blockIdx.x * 256 + threadIdx.x;
  if (idx < tot) {
    int i = idx / K_TOP;
    vals[idx] *= dis[i] * dis[inds[idx]];
  }
}

// ---------------- fused row L2-norm + fp16 cast ----------------
__global__ __launch_bounds__(256) void norm_cast_fused_k(const float* __restrict__ x,
                                                         float* __restrict__ invn,
                                                         unsigned short* __restrict__ zh, int K) {
  __shared__ __align__(16) float xr[4096];
  __shared__ float red[256];
  int r = blockIdx.x;
  const float* xp = x + (size_t)r * K;
  float ss = 0.f;
  for (int j = threadIdx.x; j < K; j += 256) { float v = xp[j]; xr[j] = v; ss += v * v; }
  red[threadIdx.x] = ss; __syncthreads();
  for (int s = 128; s > 0; s >>= 1) {
    if (threadIdx.x < s) red[threadIdx.x] += red[threadIdx.x + s];
    __syncthreads();
  }
  float inv = 1.f / fmaxf(sqrtf(red[0]), 1e-12f);
  if (threadIdx.x == 0) invn[r] = inv;
  for (int j = threadIdx.x; j < K; j += 256) {
    zh[(size_t)r * K + j] = f2h(xr[j] * inv);
  }
}

// ---------------- split-K register-tiled fp32 linear: out += X @ W (+b on split 0) ----------------
__global__ __launch_bounds__(256) void linear_splitk_k(const float* __restrict__ X,
                                                       const float* __restrict__ W,
                                                       const float* __restrict__ b,
                                                       float* __restrict__ outp, int K, int KS) {
  __shared__ float As[64][17];
  __shared__ float Ws[16][64];
  int br = blockIdx.x, ks = blockIdx.y;
  int tid = threadIdx.x, tr = tid >> 4, tc = tid & 15;
  int k0 = ks * KS, k1 = k0 + KS;
  int lrow = tid >> 2, lk = (tid & 3) * 4;
  int wrow = tid >> 4, wcol = (tid & 15) * 4;
  float acc[4][4] = {};
  for (int kb = k0; kb < k1; kb += 16) {
    __syncthreads();
    float4 xv = *(const float4*)&X[(size_t)(br * 64 + lrow) * K + kb + lk];
    As[lrow][lk + 0] = xv.x; As[lrow][lk + 1] = xv.y;
    As[lrow][lk + 2] = xv.z; As[lrow][lk + 3] = xv.w;
    *(float4*)&Ws[wrow][wcol] = *(const float4*)&W[(size_t)(kb + wrow) * 64 + wcol];
    __syncthreads();
    #pragma unroll
    for (int k = 0; k < 16; k++) {
      float a[4], w[4];
      #pragma unroll
      for (int i = 0; i < 4; i++) a[i] = As[tr * 4 + i][k];
      #pragma unroll
      for (int j = 0; j < 4; j++) w[j] = Ws[k][tc * 4 + j];
      #pragma unroll
      for (int i = 0; i < 4; i++)
        #pragma unroll
        for (int j = 0; j < 4; j++) acc[i][j] += a[i] * w[j];
    }
  }
  #pragma unroll
  for (int i = 0; i < 4; i++)
    #pragma unroll
    for (int j = 0; j < 4; j++) {
      float v = acc[i][j];
      if (ks == 0) v += b[tc * 4 + j];
      atomicAdd(&outp[(size_t)(br * 64 + tr * 4 + i) * 64 + tc * 4 + j], v);
    }
}

// ---------------- fused knn_mm pair ----------------
__global__ __launch_bounds__(256) void fuse_knn_k(const float* __restrict__ av, const int* __restrict__ ai,
                                                  const float* __restrict__ bv, const int* __restrict__ bi_,
                                                  const float* __restrict__ e, float* __restrict__ outp,
                                                  float lam) {
  int i = blockIdx.x * 4 + (threadIdx.x >> 6), d = threadIdx.x & 63;
  float sa = 0.f, sb = 0.f;
  #pragma unroll
  for (int k = 0; k < K_TOP; k++) {
    sa += av[(size_t)i * K_TOP + k] * e[(size_t)ai[(size_t)i * K_TOP + k] * 64 + d];
    sb += bv[(size_t)i * K_TOP + k] * e[(size_t)bi_[(size_t)i * K_TOP + k] * 64 + d];
  }
  outp[(size_t)i * 64 + d] = (1.f - lam) * sa + lam * sb;
}

// ---------------- attention + h ----------------
__global__ __launch_bounds__(64) void attn_k(const float* __restrict__ img_e, const float* __restrict__ txt_e,
                                             const float* __restrict__ qw1, const float* __restrict__ qb1,
                                             const float* __restrict__ qw2, float* __restrict__ h) {
  __shared__ float W1[64][64];
  __shared__ float sI[64], sT[64];
  int t = threadIdx.x; int i = blockIdx.x;
  for (int k = 0; k < 64; k++) W1[k][t] = qw1[k * 64 + t];
  sI[t] = img_e[(size_t)i * 64 + t];
  sT[t] = txt_e[(size_t)i * 64 + t];
  __syncthreads();
  float yi = qb1[t], yt = qb1[t];
  #pragma unroll 16
  for (int k = 0; k < 64; k++) { yi += sI[k] * W1[k][t]; yt += sT[k] * W1[k][t]; }
  float w2 = qw2[t];
  float pi = tanhf(yi) * w2, pt = tanhf(yt) * w2;
  for (int o = 32; o > 0; o >>= 1) { pi += __shfl_xor(pi, o, 64); pt += __shfl_xor(pt, o, 64); }
  float m = fmaxf(pi, pt);
  float ei = expf(pi - m), et = expf(pt - m);
  float den = ei + et;
  float w0 = ei / den, w1v = et / den;
  h[(size_t)i * 64 + t] = w0 * sI[t] + w1v * sT[t];
}

// ---------------- CSR build: histogram ----------------
__global__ __launch_bounds__(256) void hist_k(const int* __restrict__ rows, int* __restrict__ cnt) {
  int e = blockIdx.x * 256 + threadIdx.x;
  if (e < NNZ_E) atomicAdd(&cnt[rows[e]], 1);
}

// ---------------- CSR build: exclusive scan over 24576 bins (1 block) ----------------
__global__ __launch_bounds__(256) void scan_k(const int* __restrict__ cnt,
                                              int* __restrict__ starts,
                                              int* __restrict__ cursor) {
  __shared__ int part[256];
  int t = threadIdx.x;
  int base = t * (N_TOTAL / 256);
  int s = 0;
  for (int j = 0; j < N_TOTAL / 256; j++) s += cnt[base + j];
  part[t] = s;
  __syncthreads();
  for (int off = 1; off < 256; off <<= 1) {
    int v = part[t];
    int u = (t >= off) ? part[t - off] : 0;
    __syncthreads();
    part[t] = v + u;
    __syncthreads();
  }
  int run = (t > 0) ? part[t - 1] : 0;
  for (int j = 0; j < N_TOTAL / 256; j++) {
    starts[base + j] = run;
    cursor[base + j] = run;
    run += cnt[base + j];
  }
  if (t == 255) starts[N_TOTAL] = run;
}

// ---------------- CSR build: place edges, pre-gathering cols/vals into CSR order ----------------
__global__ __launch_bounds__(256) void place_k(const int* __restrict__ rows,
                                               const int* __restrict__ cols,
                                               const float* __restrict__ vals,
                                               int* __restrict__ cursor,
                                               int* __restrict__ cols_s,
                                               float* __restrict__ vals_s) {
  int e = blockIdx.x * 256 + threadIdx.x;
  if (e < NNZ_E) {
    int p = atomicAdd(&cursor[rows[e]], 1);
    cols_s[p] = cols[e];
    vals_s[p] = vals[e];
  }
}

// ---------------- CSR gather segment_sum: wave per row ----------------
__global__ __launch_bounds__(256) void gather_gcn_k(const int* __restrict__ starts,
                                                    const int* __restrict__ cols_s,
                                                    const float* __restrict__ vals_s,
                                                    const float* __restrict__ ego,
                                                    float* __restrict__ side) {
  int row = blockIdx.x * 4 + (threadIdx.x >> 6);
  int d = threadIdx.x & 63;
  int s = starts[row], e = starts[row + 1];
  float acc = 0.f;
  for (int i = s; i < e; i++) {
    acc += vals_s[i] * ego[(size_t)cols_s[i] * 64 + d];
  }
  side[(size_t)row * 64 + d] = acc;
}

// ---------------- GCN layer ----------------
__global__ __launch_bounds__(256) void gcn_k(const float* __restrict__ side, const float* __restrict__ ego,
                                             const float* __restrict__ gw, const float* __restrict__ gb,
                                             const float* __restrict__ bw, const float* __restrict__ bb,
                                             float* __restrict__ outp) {
  __shared__ float W1[64][64], W2[64][64];
  __shared__ float S[4][64], E[4][64];
  int t = threadIdx.x & 63, rb = threadIdx.x >> 6;
  int r = blockIdx.x * 4 + rb;
  for (int idx = threadIdx.x; idx < 4096; idx += 256) {
    W1[idx >> 6][idx & 63] = gw[idx];
    W2[idx >> 6][idx & 63] = bw[idx];
  }
  S[rb][t] = side[(size_t)r * 64 + t];
  E[rb][t] = ego[(size_t)r * 64 + t];
  __syncthreads();
  float s = gb[t], b = bb[t];
  #pragma unroll 16
  for (int k = 0; k < 64; k++) {
    float sv = S[rb][k];
    s += sv * W1[k][t];
    b += E[rb][k] * sv * W2[k][t];
  }
  outp[(size_t)r * 64 + t] = leaky01(s) + leaky01(b);
}

// ---------------- acc += l2norm(ego) rowwise ----------------
__global__ __launch_bounds__(256) void l2acc_k(const float* __restrict__ ego, float* __restrict__ acc) {
  int r = blockIdx.x * 4 + (threadIdx.x >> 6), d = threadIdx.x & 63;
  float v = ego[(size_t)r * 64 + d];
  float ss = v * v;
  for (int o = 32; o > 0; o >>= 1) ss += __shfl_xor(ss, o, 64);
  float inv = 1.f / fmaxf(sqrtf(ss), 1e-12f);
  acc[(size_t)r * 64 + d] += v * inv;
}

// ---------------- init ego/acc ----------------
__global__ __launch_bounds__(256) void init_ego_k(const float* __restrict__ ue, const float* __restrict__ ie,
                                                  float* __restrict__ ego, float* __restrict__ acc) {
  int r = blockIdx.x * 4 + (threadIdx.x >> 6), d = threadIdx.x & 63;
  float v = (r < N_USERS) ? ue[(size_t)r * 64 + d] : ie[(size_t)(r - N_USERS) * 64 + d];
  ego[(size_t)r * 64 + d] = v;
  acc[(size_t)r * 64 + d] = v;
}

// ---------------- final outputs ----------------
__global__ __launch_bounds__(256) void final_k(const float* __restrict__ acc, const float* __restrict__ h,
                                               float* __restrict__ u_g, float* __restrict__ i_g) {
  int r = blockIdx.x * 4 + (threadIdx.x >> 6), d = threadIdx.x & 63;
  float m = acc[(size_t)r * 64 + d] * (1.0f / 3.0f);
  if (r < N_USERS) {
    u_g[(size_t)r * 64 + d] = m;
  } else {
    int i = r - N_USERS;
    float hv = h[(size_t)i * 64 + d];
    float ss = hv * hv;
    for (int o = 32; o > 0; o >>= 1) ss += __shfl_xor(ss, o, 64);
    float inv = 1.f / fmaxf(sqrtf(ss), 1e-12f);
    i_g[(size_t)i * 64 + d] = m + hv * inv;
  }
}

// ---------------- host-side graph builder ----------------
static void build_graph(hipStream_t stream, const float* feats, int K, float* invn,
                        unsigned short* zh, unsigned short* sim, int stripe, int* cand,
                        const int* tile_map, float* vals, int* inds, float* dis) {
  norm_cast_fused_k<<<N_ITEMS, 256, 0, stream>>>(feats, invn, zh, K);
  if (stripe >= N_ITEMS) {
    sim_mfma_k<1><<<TRI_BLOCKS, 256, 0, stream>>>(zh, sim, K, 0, tile_map);
    tri_mirror_k<<<MIR_BLOCKS, 256, 0, stream>>>(sim);
    topk16h_k<<<N_ITEMS / 4, 256, 0, stream>>>(sim, 0, cand);
  } else {
    for (int r0 = 0; r0 < N_ITEMS; r0 += stripe) {
      int rows = (N_ITEMS - r0) < stripe ? (N_ITEMS - r0) : stripe;
      dim3 g(N_ITEMS / 128, rows / 128);
      sim_mfma_k<0><<<g, 256, 0, stream>>>(zh, sim, K, r0, tile_map);
      topk16h_k<<<rows / 4, 256, 0, stream>>>(sim, r0, cand);
    }
  }
  refine_k<<<N_ITEMS, 256, 0, stream>>>(feats, K, invn, cand, vals, inds, dis);
  int tot = N_ITEMS * K_TOP;
  scale_vals_k<<<(tot + 255) / 256, 256, 0, stream>>>(vals, inds, dis, tot);
}

extern "C" void kernel_launch(void* const* d_in, const int* in_sizes, int n_in,
                              void* d_out, int out_size, void* d_ws, size_t ws_size,
                              hipStream_t stream) {
  const int*   adj_rows   = (const int*)d_in[0];
  const int*   adj_cols   = (const int*)d_in[1];
  const float* adj_vals   = (const float*)d_in[2];
  const float* image_feats= (const float*)d_in[3];
  const float* text_feats = (const float*)d_in[4];
  const float* user_emb   = (const float*)d_in[5];
  const float* item_emb   = (const float*)d_in[6];
  const float* img_w      = (const float*)d_in[7];
  const float* img_b      = (const float*)d_in[8];
  const float* txt_w      = (const float*)d_in[9];
  const float* txt_b      = (const float*)d_in[10];
  const float* q_w1       = (const float*)d_in[11];
  const float* q_b1       = (const float*)d_in[12];
  const float* q_w2       = (const float*)d_in[13];
  const float* gc_w       = (const float*)d_in[14];
  const float* gc_b       = (const float*)d_in[15];
  const float* bi_w       = (const float*)d_in[16];
  const float* bi_b       = (const float*)d_in[17];

  float* out  = (float*)d_out;
  float* u_g  = out;
  float* i_g  = u_g + (size_t)N_USERS * 64;
  float* imgE = i_g + (size_t)N_ITEMS * 64;
  float* txtE = imgE + (size_t)N_ITEMS * 64;
  float* hOut = txtE + (size_t)N_ITEMS * 64;

  // ---- workspace layout (floats) ----
  float* W = (float*)d_ws;
  size_t off = 0;
  auto alloc = [&](size_t n) { float* q = W + off; off += n; return q; };
  float* inv_io = alloc(N_ITEMS);
  float* inv_to = alloc(N_ITEMS);
  float* inv_in = alloc(N_ITEMS);
  float* inv_tn = alloc(N_ITEMS);
  float* img_f  = alloc((size_t)N_ITEMS * 64);
  float* txt_f  = alloc((size_t)N_ITEMS * 64);
  float* vals0 = alloc(N_ITEMS * K_TOP); int* inds0 = (int*)alloc(N_ITEMS * K_TOP);
  float* vals1 = alloc(N_ITEMS * K_TOP); int* inds1 = (int*)alloc(N_ITEMS * K_TOP);
  float* vals2 = alloc(N_ITEMS * K_TOP); int* inds2 = (int*)alloc(N_ITEMS * K_TOP);
  float* vals3 = alloc(N_ITEMS * K_TOP); int* inds3 = (int*)alloc(N_ITEMS * K_TOP);
  float* dis0 = alloc(N_ITEMS);
  float* dis1 = alloc(N_ITEMS);
  float* dis2 = alloc(N_ITEMS);
  float* dis3 = alloc(N_ITEMS);
  int*   cand = (int*)alloc((size_t)N_ITEMS * N_CAND);
  int*   tile_map = (int*)alloc(TRI_BLOCKS);
  float* ego_a = alloc((size_t)N_TOTAL * 64);
  float* ego_b = alloc((size_t)N_TOTAL * 64);
  float* side  = alloc((size_t)N_TOTAL * 64);
  float* acc   = alloc((size_t)N_TOTAL * 64);
  int* csr_cnt    = (int*)alloc(N_TOTAL);
  int* csr_starts = (int*)alloc(N_TOTAL + 1);
  int* csr_cursor = (int*)alloc(N_TOTAL);
  int* csr_cols   = (int*)alloc(NNZ_E);
  float* csr_vals = alloc(NNZ_E);
  unsigned short* zh = (unsigned short*)alloc(((size_t)N_ITEMS * IMG_DIM) / 2);  // 64MB fp16
  unsigned short* sim = (unsigned short*)(W + off);

  size_t used_bytes = off * 4;
  size_t avail_b = (ws_size > used_bytes) ? (ws_size - used_bytes) : 0;
  long stripe_l = (long)((avail_b / ((size_t)N_ITEMS * 2)) / 128) * 128;
  if (stripe_l > N_ITEMS) stripe_l = N_ITEMS;
  if (stripe_l < 128) stripe_l = 128;
  int stripe = (int)stripe_l;

  // ---- one-time tables ----
  fill_map_k<<<(TRI_BLOCKS + 255) / 256, 256, 0, stream>>>(tile_map);

  // ---- CSR build (once, reused by both GCN layers) ----
  hipMemsetAsync(csr_cnt, 0, N_TOTAL * sizeof(int), stream);
  hist_k<<<(NNZ_E + 255) / 256, 256, 0, stream>>>(adj_rows, csr_cnt);
  scan_k<<<1, 256, 0, stream>>>(csr_cnt, csr_starts, csr_cursor);
  place_k<<<(NNZ_E + 255) / 256, 256, 0, stream>>>(adj_rows, adj_cols, adj_vals,
                                                   csr_cursor, csr_cols, csr_vals);

  // ---- 4 KNN graphs ----
  build_graph(stream, image_feats, IMG_DIM, inv_io, zh, sim, stripe, cand, tile_map, vals0, inds0, dis0);
  build_graph(stream, text_feats,  TXT_DIM, inv_to, zh, sim, stripe, cand, tile_map, vals1, inds1, dis1);

  hipMemsetAsync(img_f, 0, (size_t)N_ITEMS * 64 * sizeof(float), stream);
  hipMemsetAsync(txt_f, 0, (size_t)N_ITEMS * 64 * sizeof(float), stream);
  linear_splitk_k<<<dim3(N_ITEMS / 64, 4), 256, 0, stream>>>(image_feats, img_w, img_b, img_f, IMG_DIM, IMG_DIM / 4);
  linear_splitk_k<<<dim3(N_ITEMS / 64, 4), 256, 0, stream>>>(text_feats,  txt_w, txt_b, txt_f, TXT_DIM, TXT_DIM / 4);

  build_graph(stream, img_f, 64, inv_in, zh, sim, stripe, cand, tile_map, vals2, inds2, dis2);
  build_graph(stream, txt_f, 64, inv_tn, zh, sim, stripe, cand, tile_map, vals3, inds3, dis3);

  // ---- img_e / txt_e ----
  const float lam = 0.9f;
  fuse_knn_k<<<N_ITEMS / 4, 256, 0, stream>>>(vals2, inds2, vals0, inds0, item_emb, imgE, lam);
  fuse_knn_k<<<N_ITEMS / 4, 256, 0, stream>>>(vals3, inds3, vals1, inds1, item_emb, txtE, lam);

  // ---- attention + h ----
  attn_k<<<N_ITEMS, 64, 0, stream>>>(imgE, txtE, q_w1, q_b1, q_w2, hOut);

  // ---- GCN ----
  init_ego_k<<<N_TOTAL / 4, 256, 0, stream>>>(user_emb, item_emb, ego_a, acc);

  // layer 0
  gather_gcn_k<<<N_TOTAL / 4, 256, 0, stream>>>(csr_starts, csr_cols, csr_vals, ego_a, side);
  gcn_k<<<N_TOTAL / 4, 256, 0, stream>>>(side, ego_a, gc_w, gc_b, bi_w, bi_b, ego_b);
  l2acc_k<<<N_TOTAL / 4, 256, 0, stream>>>(ego_b, acc);

  // layer 1
  gather_gcn_k<<<N_TOTAL / 4, 256, 0, stream>>>(csr_starts, csr_cols, csr_vals, ego_b, side);
  gcn_k<<<N_TOTAL / 4, 256, 0, stream>>>(side, ego_b, gc_w + 4096, gc_b + 64, bi_w + 4096, bi_b + 64, ego_a);
  l2acc_k<<<N_TOTAL / 4, 256, 0, stream>>>(ego_a, acc);

  // ---- final outputs ----
  final_k<<<N_TOTAL / 4, 256, 0, stream>>>(acc, hOut, u_g, i_g);
}